// Round 14
// baseline (1079.902 us; speedup 1.0000x reference)
//
#include <hip/hip_runtime.h>
#include <hip/hip_bf16.h>
#include <stdint.h>

typedef __attribute__((ext_vector_type(8))) short short8;
typedef __attribute__((ext_vector_type(2))) short s16x2;
typedef __attribute__((ext_vector_type(4))) float f32x4;
typedef unsigned short u16;

#define N_E 1000000
#define N_T 2000000

// ---------------- workspace layout (bytes) ----------------
#define OFF_PSUM 0ULL                      // 1e6*64 bf16 = 128,000,000
#define OFF_CNT  128000000ULL              // 1e6*4
#define OFF_EBF  132000000ULL              // 1e6*64*2 = 128,000,000 (ends 260e6)
#define OFF_WT1  388000000ULL              // W1^T [n][k]: 128*160*2 = 40960
#define OFF_WT2  (OFF_WT1 + 40960ULL)      // W2'^T [n][k]: 128*128*2 = 32768
#define OFF_WP3  (OFF_WT2 + 32768ULL)      // W3' frag-packed [kb][n][8]: 16384
#define OFF_S2   (OFF_WP3 + 16384ULL)      // 128*4
#define OFF_C2   (OFF_S2 + 512ULL)
#define OFF_S3   (OFF_C2 + 512ULL)         // 64*4
#define OFF_T3   (OFF_S3 + 256ULL)         // 64*4

// ---------------- LDS layout (bytes), 64-trip block (R5 verbatim) ----------------
#define LDS_HM   0        // [64 trip][256B] swizzled; H, then M aliases it
#define LDS_TAIL 16384    // [64 trip][64B] geo tail, swizzled (r&3)<<4
#define LDS_P1S  20480    // float[64][2]
#define LDS_P1Q  20992
#define LDS_P2S  21504
#define LDS_P2Q  22016
#define LDS_EIJ  22528    // int[64]
#define LDS_TOTAL 22784

__device__ __forceinline__ u16 f2bf(float f) {
  union { float f; uint32_t u; } c; c.f = f;
  uint32_t u = c.u;
  return (u16)((u + 0x7FFFu + ((u >> 16) & 1u)) >> 16);  // RNE
}
__device__ __forceinline__ uint32_t pkbf(float lo, float hi) {
  float2 t; t.x = lo; t.y = hi;
  __hip_bfloat162 h = __float22bfloat162_rn(t);
  uint32_t u; __builtin_memcpy(&u, &h, 4);
  return u;
}
__device__ __forceinline__ float blo(uint32_t u) {
  union { uint32_t u; float f; } c; c.u = u << 16; return c.f;
}
__device__ __forceinline__ float bhi(uint32_t u) {
  union { uint32_t u; float f; } c; c.u = u & 0xffff0000u; return c.f;
}
__device__ __forceinline__ float silu(float y) {
  return y * __builtin_amdgcn_rcpf(1.0f + __expf(-y));
}

// packed bf16x2 global atomic add (CDNA4 global_atomic_pk_add_bf16)
#if __has_builtin(__builtin_amdgcn_global_atomic_fadd_v2bf16)
__device__ __forceinline__ void atomic_pk_add_bf16(u16* p, uint32_t v) {
  s16x2 d; __builtin_memcpy(&d, &v, 4);
  __builtin_amdgcn_global_atomic_fadd_v2bf16(
      (__attribute__((address_space(1))) s16x2*)(uintptr_t)p, d);
}
#else
__device__ __forceinline__ void atomic_pk_add_bf16(u16* p, uint32_t v) {
  uint32_t* ap = (uint32_t*)p;
  uint32_t old = __atomic_load_n(ap, __ATOMIC_RELAXED), assumed;
  do {
    assumed = old;
    uint32_t nv = pkbf(blo(assumed) + blo(v), bhi(assumed) + bhi(v));
    old = atomicCAS(ap, assumed, nv);
  } while (old != assumed);
}
#endif

#define MFMA16(a, b, c) __builtin_amdgcn_mfma_f32_16x16x32_bf16((a), (b), (c), 0, 0, 0)

// ---------------- prep kernels (R5 ordering: memset first, conv last) ----------------

__global__ __launch_bounds__(256) void k_conv_edge(const float* __restrict__ ef,
                                                   u16* __restrict__ ebf) {
  int i = blockIdx.x * 256 + threadIdx.x;  // < 16,000,000
  float4 v = ((const float4*)ef)[i];
  ushort4 o;
  o.x = f2bf(v.x); o.y = f2bf(v.y); o.z = f2bf(v.z); o.w = f2bf(v.w);
  ((ushort4*)ebf)[i] = o;
}

// wt1[n*160+k] = W1[k,n] (k<132 else 0)   [transposed row-major]
// wt2[n*128+k] = g1[k]*W2[k,n]            [transposed row-major]
// wp3[(k>>3)*64 + n][k&7] = g2[k]*W3[k,n] [B-fragment packed]
__global__ __launch_bounds__(256) void k_pack_w(const float* __restrict__ W1,
                                                const float* __restrict__ W2,
                                                const float* __restrict__ W3,
                                                const float* __restrict__ g1,
                                                const float* __restrict__ g2,
                                                u16* __restrict__ wt1,
                                                u16* __restrict__ wt2,
                                                u16* __restrict__ wp3) {
  int i = blockIdx.x * 256 + threadIdx.x;  // < 45056
  if (i < 20480) {
    int n = i / 160, k = i - n * 160;
    wt1[i] = (k < 132) ? f2bf(W1[k * 128 + n]) : (u16)0;
  } else if (i < 36864) {
    int i2 = i - 20480;
    int n = i2 >> 7, k = i2 & 127;
    wt2[i2] = f2bf(g1[k] * W2[k * 128 + n]);
  } else if (i < 45056) {
    int i3 = i - 36864;
    int j = i3 & 7, n = (i3 >> 3) & 63, kb = i3 >> 9;
    int k = kb * 8 + j;
    wp3[i3] = f2bf(g2[k] * W3[k * 64 + n]);
  }
}

__global__ __launch_bounds__(256) void k_pack_vec(
    const float* __restrict__ W2, const float* __restrict__ W3,
    const float* __restrict__ g1, const float* __restrict__ be1, const float* __restrict__ b2,
    const float* __restrict__ g2, const float* __restrict__ be2,
    float* __restrict__ s2, float* __restrict__ c2,
    float* __restrict__ s3, float* __restrict__ t3) {
  int t = threadIdx.x;
  if (t < 128) {
    float a = 0.f, b = 0.f;
    for (int k = 0; k < 128; ++k) {
      float w = W2[k * 128 + t];
      a += g1[k] * w; b += be1[k] * w;
    }
    s2[t] = a; c2[t] = b + b2[t];
  } else if (t < 192) {
    int n = t - 128;
    float a = 0.f, b = 0.f;
    for (int k = 0; k < 128; ++k) {
      float w = W3[k * 64 + n];
      a += g2[k] * w; b += be2[k] * w;
    }
    s3[n] = a; t3[n] = b;
  }
}

// ---------------- main triplet kernel (R13 verbatim; 6 blocks/CU probe) ----------------
// One-variable experiment: __launch_bounds__(256,5) -> (256,6).
// Spill litmus: WRITE_SIZE >450 MB => revert to (256,5) as the floor.

__global__ __launch_bounds__(256, 6) void k_triplet(
    const u16* __restrict__ ebf, const int* __restrict__ tidx,
    const float* __restrict__ geo,
    const u16* __restrict__ wt1, const u16* __restrict__ wt2, const u16* __restrict__ wp3,
    const float* __restrict__ b1,
    const float* __restrict__ s2v, const float* __restrict__ c2v,
    const float* __restrict__ s3v,
    u16* __restrict__ psum, float* __restrict__ cnt) {
  __shared__ __align__(16) char smem[LDS_TOTAL];
  float* P1S = (float*)(smem + LDS_P1S);
  float* P1Q = (float*)(smem + LDS_P1Q);
  float* P2S = (float*)(smem + LDS_P2S);
  float* P2Q = (float*)(smem + LDS_P2Q);
  int* EIJ = (int*)(smem + LDS_EIJ);

  const int tid = threadIdx.x;
  const int wave = tid >> 6, lane = tid & 63;
  const int wm = wave >> 1, wn = wave & 1;
  const int l15 = lane & 15, lg = lane >> 4;
  const int t0 = blockIdx.x * 64;

  // per-lane trips for the two B-fragment columns (f=0,1)
  const int tA = wn * 32 + l15;
  const int tB = tA + 16;
  int2 pA = ((const int2*)tidx)[t0 + tA];
  int2 pB = ((const int2*)tidx)[t0 + tB];

  // deep-prefetch 8 global B-frag gathers (16B each) for GEMM1 (k<128 part)
  const short8* eb = (const short8*)ebf;
  short8 bxA0 = eb[(size_t)pA.x * 8 + lg];
  short8 bxA1 = eb[(size_t)pA.x * 8 + 4 + lg];
  short8 bxA2 = eb[(size_t)pA.y * 8 + lg];
  short8 bxA3 = eb[(size_t)pA.y * 8 + 4 + lg];
  short8 bxB0 = eb[(size_t)pB.x * 8 + lg];
  short8 bxB1 = eb[(size_t)pB.x * 8 + 4 + lg];
  short8 bxB2 = eb[(size_t)pB.y * 8 + lg];
  short8 bxB3 = eb[(size_t)pB.y * 8 + 4 + lg];

  // stage EIJ + geo tail ([64][64B], swizzle (r&3)<<4)
  if (tid < 64) {
    int2 p = ((const int2*)tidx)[t0 + tid];
    EIJ[tid] = p.x;
    atomicAdd(&cnt[p.x], 1.0f);
    float4 gq = ((const float4*)geo)[t0 + tid];
    uint2 gw; gw.x = pkbf(gq.x, gq.y); gw.y = pkbf(gq.z, gq.w);
    char* tp = smem + LDS_TAIL + tid * 64;
    const int ts = (tid & 3) << 4;
    *(uint2*)(tp + (0 ^ ts)) = gw;
    *(uint2*)(tp + (0 ^ ts) + 8) = (uint2){0, 0};
    *(uint4*)(tp + (16 ^ ts)) = (uint4){0, 0, 0, 0};
    *(uint4*)(tp + (32 ^ ts)) = (uint4){0, 0, 0, 0};
    *(uint4*)(tp + (48 ^ ts)) = (uint4){0, 0, 0, 0};
  }
  __syncthreads();

  short8 btA = *(const short8*)(smem + LDS_TAIL + tA * 64 + ((lg * 16) ^ ((tA & 3) << 4)));
  short8 btB = *(const short8*)(smem + LDS_TAIL + tB * 64 + ((lg * 16) ^ ((tB & 3) << 4)));

  // ---- GEMM1: C1' = W1^T x X^T  (K=160) ----
  f32x4 acc[4][2];
#pragma unroll
  for (int mf = 0; mf < 4; ++mf) { acc[mf][0] = (f32x4)0.f; acc[mf][1] = (f32x4)0.f; }
  const short8* w1p = (const short8*)wt1;
#pragma unroll
  for (int s5 = 0; s5 < 5; ++s5) {
    short8 b0, b1x;
    if (s5 == 0) { b0 = bxA0; b1x = bxB0; }
    else if (s5 == 1) { b0 = bxA1; b1x = bxB1; }
    else if (s5 == 2) { b0 = bxA2; b1x = bxB2; }
    else if (s5 == 3) { b0 = bxA3; b1x = bxB3; }
    else { b0 = btA; b1x = btB; }
#pragma unroll
    for (int mf = 0; mf < 4; ++mf) {
      short8 aw = w1p[(wm * 64 + mf * 16 + l15) * 20 + s5 * 4 + lg];
      acc[mf][0] = MFMA16(aw, b0, acc[mf][0]);
      acc[mf][1] = MFMA16(aw, b1x, acc[mf][1]);
    }
  }

  // epilogue1: bias+silu; lane-local stats; write H^T [trip][n] bf16
  {
    float4 b1f[4];
#pragma unroll
    for (int mf = 0; mf < 4; ++mf)
      b1f[mf] = *(const float4*)(b1 + wm * 64 + mf * 16 + lg * 4);
    float st[2] = {0.f, 0.f}, sq[2] = {0.f, 0.f};
#pragma unroll
    for (int mf = 0; mf < 4; ++mf)
#pragma unroll
      for (int f = 0; f < 2; ++f)
#pragma unroll
        for (int q2 = 0; q2 < 4; ++q2) {
          float v = silu(acc[mf][f][q2] + b1f[mf][q2]);
          acc[mf][f][q2] = v;
          st[f] += v; sq[f] += v * v;
        }
#pragma unroll
    for (int f = 0; f < 2; ++f) {
      st[f] += __shfl_xor(st[f], 16); sq[f] += __shfl_xor(sq[f], 16);
      st[f] += __shfl_xor(st[f], 32); sq[f] += __shfl_xor(sq[f], 32);
    }
    if (lg == 0) {
#pragma unroll
      for (int f = 0; f < 2; ++f) {
        int trip = wn * 32 + f * 16 + l15;
        P1S[trip * 2 + wm] = st[f];
        P1Q[trip * 2 + wm] = sq[f];
      }
    }
#pragma unroll
    for (int mf = 0; mf < 4; ++mf)
#pragma unroll
      for (int f = 0; f < 2; ++f) {
        int trip = wn * 32 + f * 16 + l15;
        uint2 w;
        w.x = pkbf(acc[mf][f][0], acc[mf][f][1]);
        w.y = pkbf(acc[mf][f][2], acc[mf][f][3]);
        *(uint2*)(smem + LDS_HM + trip * 256 +
                  ((wm * 128 + mf * 32 + lg * 8) ^ ((trip & 7) << 4))) = w;
      }
  }
  __syncthreads();

  // ---- GEMM2: C2' = W2'^T x H^T  (K=128) ----
#pragma unroll
  for (int mf = 0; mf < 4; ++mf) { acc[mf][0] = (f32x4)0.f; acc[mf][1] = (f32x4)0.f; }
  const short8* w2p = (const short8*)wt2;
#pragma unroll
  for (int s4 = 0; s4 < 4; ++s4) {
    short8 bx0, bx1;
    {
      int trip = wn * 32 + l15;
      bx0 = *(const short8*)(smem + LDS_HM + trip * 256 +
                             ((s4 * 64 + lg * 16) ^ ((trip & 7) << 4)));
      int trip2 = trip + 16;
      bx1 = *(const short8*)(smem + LDS_HM + trip2 * 256 +
                             ((s4 * 64 + lg * 16) ^ ((trip2 & 7) << 4)));
    }
#pragma unroll
    for (int mf = 0; mf < 4; ++mf) {
      short8 aw = w2p[(wm * 64 + mf * 16 + l15) * 16 + s4 * 4 + lg];
      acc[mf][0] = MFMA16(aw, bx0, acc[mf][0]);
      acc[mf][1] = MFMA16(aw, bx1, acc[mf][1]);
    }
  }

  // epilogue2: folded LN1 + silu; lane-local stats into P2
  {
    float4 s2f[4], c2f[4];
#pragma unroll
    for (int mf = 0; mf < 4; ++mf) {
      s2f[mf] = *(const float4*)(s2v + wm * 64 + mf * 16 + lg * 4);
      c2f[mf] = *(const float4*)(c2v + wm * 64 + mf * 16 + lg * 4);
    }
    float mu[2], inv[2];
#pragma unroll
    for (int f = 0; f < 2; ++f) {
      int trip = wn * 32 + f * 16 + l15;
      float sm = P1S[trip * 2] + P1S[trip * 2 + 1];
      float qq = P1Q[trip * 2] + P1Q[trip * 2 + 1];
      mu[f] = sm * 0.0078125f;
      inv[f] = rsqrtf(fmaxf(qq * 0.0078125f - mu[f] * mu[f], 0.f) + 1e-5f);
    }
    float st[2] = {0.f, 0.f}, sq[2] = {0.f, 0.f};
#pragma unroll
    for (int mf = 0; mf < 4; ++mf)
#pragma unroll
      for (int f = 0; f < 2; ++f)
#pragma unroll
        for (int q2 = 0; q2 < 4; ++q2) {
          float y = inv[f] * (acc[mf][f][q2] - mu[f] * s2f[mf][q2]) + c2f[mf][q2];
          float v = silu(y);
          acc[mf][f][q2] = v;
          st[f] += v; sq[f] += v * v;
        }
#pragma unroll
    for (int f = 0; f < 2; ++f) {
      st[f] += __shfl_xor(st[f], 16); sq[f] += __shfl_xor(sq[f], 16);
      st[f] += __shfl_xor(st[f], 32); sq[f] += __shfl_xor(sq[f], 32);
    }
    if (lg == 0) {
#pragma unroll
      for (int f = 0; f < 2; ++f) {
        int trip = wn * 32 + f * 16 + l15;
        P2S[trip * 2 + wm] = st[f];
        P2Q[trip * 2 + wm] = sq[f];
      }
    }
  }
  __syncthreads();  // all GEMM2 H-reads done; P2 visible

  // write M [trip][n] bf16 into HM region (aliases H)
#pragma unroll
  for (int mf = 0; mf < 4; ++mf)
#pragma unroll
    for (int f = 0; f < 2; ++f) {
      int trip = wn * 32 + f * 16 + l15;
      uint2 w;
      w.x = pkbf(acc[mf][f][0], acc[mf][f][1]);
      w.y = pkbf(acc[mf][f][2], acc[mf][f][3]);
      *(uint2*)(smem + LDS_HM + trip * 256 +
                ((wm * 128 + mf * 32 + lg * 8) ^ ((trip & 7) << 4))) = w;
    }
  __syncthreads();  // M visible

  // ---- GEMM3 (un-transposed): C3 = M x W3'  (K=128, N=64) ----
  f32x4 acc3[4];
#pragma unroll
  for (int nf = 0; nf < 4; ++nf) acc3[nf] = (f32x4)0.f;
  const short8* wb3 = (const short8*)wp3;
#pragma unroll
  for (int s4 = 0; s4 < 4; ++s4) {
    int row = wave * 16 + l15;
    short8 a = *(const short8*)(smem + LDS_HM + row * 256 +
                                ((s4 * 64 + lg * 16) ^ ((row & 7) << 4)));
#pragma unroll
    for (int nf = 0; nf < 4; ++nf) {
      short8 b = wb3[(s4 * 4 + lg) * 64 + nf * 16 + l15];
      acc3[nf] = MFMA16(a, b, acc3[nf]);
    }
  }

  // epilogue3: folded LN2; pair cols across lane-pairs; packed-bf16 atomics.
  {
    float s3c[4];
#pragma unroll
    for (int nf = 0; nf < 4; ++nf) s3c[nf] = s3v[nf * 16 + l15];
    float yv[4][4], yn[4][4];   // [nf][q] — all indices compile-time below
#pragma unroll
    for (int q2 = 0; q2 < 4; ++q2) {
      int row = wave * 16 + lg * 4 + q2;
      float sm = P2S[row * 2] + P2S[row * 2 + 1];
      float qq = P2Q[row * 2] + P2Q[row * 2 + 1];
      float mu = sm * 0.0078125f;
      float inv = rsqrtf(fmaxf(qq * 0.0078125f - mu * mu, 0.f) + 1e-5f);
#pragma unroll
      for (int nf = 0; nf < 4; ++nf)
        yv[nf][q2] = inv * (acc3[nf][q2] - mu * s3c[nf]);
    }
#pragma unroll
    for (int q2 = 0; q2 < 4; ++q2)
#pragma unroll
      for (int nf = 0; nf < 4; ++nf)
        yn[nf][q2] = __shfl_xor(yv[nf][q2], 1);
    const int odd = l15 & 1;
    const int colp = l15 & ~1;   // paired column base within 16
#pragma unroll
    for (int dq = 0; dq < 2; ++dq) {
      int rowE = wave * 16 + lg * 4 + dq;       // even-lane row (q=dq)
      int rowO = rowE + 2;                      // odd-lane row (q=2+dq)
      int row = odd ? rowO : rowE;
      u16* base = psum + (size_t)EIJ[row] * 64 + colp;
#pragma unroll
      for (int nf = 0; nf < 4; ++nf) {
        float lo = odd ? yn[nf][2 + dq] : yv[nf][dq];   // col 2k
        float hi = odd ? yv[nf][2 + dq] : yn[nf][dq];   // col 2k+1
        atomic_pk_add_bf16(base + nf * 16, pkbf(lo, hi));
      }
    }
  }
}

// ---------------- finalize ----------------
// out = LN(bf16(ef) + psum/max(cnt,1) + b3 + (cnt>0 ? t3 : 0), gn, bn)

__global__ __launch_bounds__(256) void k_final(
    const u16* __restrict__ psum, const float* __restrict__ cnt,
    const u16* __restrict__ ebf, const float* __restrict__ b3,
    const float* __restrict__ t3, const float* __restrict__ gn,
    const float* __restrict__ bn, float* __restrict__ out) {
  int g = blockIdx.x * 256 + threadIdx.x;  // 4e6 threads, 4 lanes/edge
  int e = g >> 2, s = g & 3;
  float cv = cnt[e];
  float ic = 1.0f / fmaxf(cv, 1.0f);
  float tw = (cv > 0.f) ? 1.0f : 0.0f;
  float x[16];
  const uint4* ps = (const uint4*)(psum + (size_t)e * 64 + s * 16);
  const uint4* fb = (const uint4*)(ebf + (size_t)e * 64 + s * 16);
  const float4* p3 = (const float4*)(b3 + s * 16);
  const float4* pt = (const float4*)(t3 + s * 16);
  uint4 a0 = ps[0], a1 = ps[1];
  uint4 e0 = fb[0], e1 = fb[1];
  float av[16] = {blo(a0.x), bhi(a0.x), blo(a0.y), bhi(a0.y),
                  blo(a0.z), bhi(a0.z), blo(a0.w), bhi(a0.w),
                  blo(a1.x), bhi(a1.x), blo(a1.y), bhi(a1.y),
                  blo(a1.z), bhi(a1.z), blo(a1.w), bhi(a1.w)};
  float ev[16] = {blo(e0.x), bhi(e0.x), blo(e0.y), bhi(e0.y),
                  blo(e0.z), bhi(e0.z), blo(e0.w), bhi(e0.w),
                  blo(e1.x), bhi(e1.x), blo(e1.y), bhi(e1.y),
                  blo(e1.z), bhi(e1.z), blo(e1.w), bhi(e1.w)};
#pragma unroll
  for (int i = 0; i < 4; ++i) {
    float4 c = p3[i], d = pt[i];
    x[4 * i + 0] = ev[4 * i + 0] + av[4 * i + 0] * ic + c.x + tw * d.x;
    x[4 * i + 1] = ev[4 * i + 1] + av[4 * i + 1] * ic + c.y + tw * d.y;
    x[4 * i + 2] = ev[4 * i + 2] + av[4 * i + 2] * ic + c.z + tw * d.z;
    x[4 * i + 3] = ev[4 * i + 3] + av[4 * i + 3] * ic + c.w + tw * d.w;
  }
  float sum = 0.f, ss = 0.f;
#pragma unroll
  for (int i = 0; i < 16; ++i) { sum += x[i]; ss += x[i] * x[i]; }
  sum += __shfl_xor(sum, 1); ss += __shfl_xor(ss, 1);
  sum += __shfl_xor(sum, 2); ss += __shfl_xor(ss, 2);
  float mu = sum * (1.0f / 64.0f);
  float inv = rsqrtf(ss * (1.0f / 64.0f) - mu * mu + 1e-5f);
  float4* po = (float4*)(out + (size_t)e * 64 + s * 16);
#pragma unroll
  for (int i = 0; i < 4; ++i) {
    float4 gv = ((const float4*)(gn + s * 16))[i];
    float4 bv = ((const float4*)(bn + s * 16))[i];
    float4 o;
    o.x = (x[4 * i + 0] - mu) * inv * gv.x + bv.x;
    o.y = (x[4 * i + 1] - mu) * inv * gv.y + bv.y;
    o.z = (x[4 * i + 2] - mu) * inv * gv.z + bv.z;
    o.w = (x[4 * i + 3] - mu) * inv * gv.w + bv.w;
    po[i] = o;
  }
}

extern "C" void kernel_launch(void* const* d_in, const int* in_sizes, int n_in,
                              void* d_out, int out_size, void* d_ws, size_t ws_size,
                              hipStream_t stream) {
  const float* edge_feat = (const float*)d_in[0];
  const int* tidx = (const int*)d_in[1];
  const float* geo = (const float*)d_in[2];
  const float* W1 = (const float*)d_in[3];
  const float* b1 = (const float*)d_in[4];
  const float* g1 = (const float*)d_in[5];
  const float* be1 = (const float*)d_in[6];
  const float* W2 = (const float*)d_in[7];
  const float* b2 = (const float*)d_in[8];
  const float* g2 = (const float*)d_in[9];
  const float* be2 = (const float*)d_in[10];
  const float* W3 = (const float*)d_in[11];
  const float* b3 = (const float*)d_in[12];
  const float* gn = (const float*)d_in[13];
  const float* bn = (const float*)d_in[14];

  char* ws = (char*)d_ws;
  u16* psum = (u16*)(ws + OFF_PSUM);
  float* cnt = (float*)(ws + OFF_CNT);
  u16* ebf = (u16*)(ws + OFF_EBF);
  u16* wt1 = (u16*)(ws + OFF_WT1);
  u16* wt2 = (u16*)(ws + OFF_WT2);
  u16* wp3 = (u16*)(ws + OFF_WP3);
  float* s2 = (float*)(ws + OFF_S2);
  float* c2 = (float*)(ws + OFF_C2);
  float* s3 = (float*)(ws + OFF_S3);
  float* t3 = (float*)(ws + OFF_T3);
  float* out = (float*)d_out;

  hipMemsetAsync(ws, 0, 132000000ULL, stream);  // psum (bf16) + cnt
  k_conv_edge<<<62500, 256, 0, stream>>>(edge_feat, ebf);
  k_pack_w<<<176, 256, 0, stream>>>(W1, W2, W3, g1, g2, wt1, wt2, wp3);
  k_pack_vec<<<1, 256, 0, stream>>>(W2, W3, g1, be1, b2, g2, be2, s2, c2, s3, t3);

  k_triplet<<<31250, 256, 0, stream>>>(ebf, tidx, geo, wt1, wt2, wp3,
                                       b1, s2, c2, s3, psum, cnt);
  k_final<<<15625, 256, 0, stream>>>(psum, cnt, ebf, b3, t3, gn, bn, out);
}

// Round 15
// 983.235 us; speedup vs baseline: 1.0983x; 1.0983x over previous
//
#include <hip/hip_runtime.h>
#include <hip/hip_bf16.h>
#include <stdint.h>

typedef __attribute__((ext_vector_type(8))) short short8;
typedef __attribute__((ext_vector_type(2))) short s16x2;
typedef __attribute__((ext_vector_type(4))) float f32x4;
typedef unsigned short u16;

#define N_E 1000000
#define N_T 2000000

// ---------------- workspace layout (bytes) ----------------
#define OFF_PSUM 0ULL                      // 1e6*64 bf16 = 128,000,000
#define OFF_CNT  128000000ULL              // 1e6*4
#define OFF_EBF  132000000ULL              // 1e6*64*2 = 128,000,000 (ends 260e6)
#define OFF_WT1  388000000ULL              // W1^T [n][k]: 128*160*2 = 40960
#define OFF_WT2  (OFF_WT1 + 40960ULL)      // W2'^T [n][k]: 128*128*2 = 32768
#define OFF_WP3  (OFF_WT2 + 32768ULL)      // W3' frag-packed [kb][n][8]: 16384
#define OFF_S2   (OFF_WP3 + 16384ULL)      // 128*4
#define OFF_C2   (OFF_S2 + 512ULL)
#define OFF_S3   (OFF_C2 + 512ULL)         // 64*4
#define OFF_T3   (OFF_S3 + 256ULL)         // 64*4

// ---------------- LDS layout (bytes), 64-trip block ----------------
#define LDS_HM   0        // [64 trip][256B] swizzled; H, then M aliases it
#define LDS_TAIL 16384    // [64 trip][64B] geo tail, swizzled (r&3)<<4
#define LDS_P1S  20480    // float[64][2]
#define LDS_P1Q  20992
#define LDS_P2S  21504
#define LDS_P2Q  22016
#define LDS_EIJ  22528    // int[64]
#define LDS_TOTAL 22784

__device__ __forceinline__ u16 f2bf(float f) {
  union { float f; uint32_t u; } c; c.f = f;
  uint32_t u = c.u;
  return (u16)((u + 0x7FFFu + ((u >> 16) & 1u)) >> 16);  // RNE
}
__device__ __forceinline__ uint32_t pkbf(float lo, float hi) {
  float2 t; t.x = lo; t.y = hi;
  __hip_bfloat162 h = __float22bfloat162_rn(t);
  uint32_t u; __builtin_memcpy(&u, &h, 4);
  return u;
}
__device__ __forceinline__ float blo(uint32_t u) {
  union { uint32_t u; float f; } c; c.u = u << 16; return c.f;
}
__device__ __forceinline__ float bhi(uint32_t u) {
  union { uint32_t u; float f; } c; c.u = u & 0xffff0000u; return c.f;
}
__device__ __forceinline__ float silu(float y) {
  return y * __builtin_amdgcn_rcpf(1.0f + __expf(-y));
}

// packed bf16x2 global atomic add (CDNA4 global_atomic_pk_add_bf16)
#if __has_builtin(__builtin_amdgcn_global_atomic_fadd_v2bf16)
__device__ __forceinline__ void atomic_pk_add_bf16(u16* p, uint32_t v) {
  s16x2 d; __builtin_memcpy(&d, &v, 4);
  __builtin_amdgcn_global_atomic_fadd_v2bf16(
      (__attribute__((address_space(1))) s16x2*)(uintptr_t)p, d);
}
#else
__device__ __forceinline__ void atomic_pk_add_bf16(u16* p, uint32_t v) {
  uint32_t* ap = (uint32_t*)p;
  uint32_t old = __atomic_load_n(ap, __ATOMIC_RELAXED), assumed;
  do {
    assumed = old;
    uint32_t nv = pkbf(blo(assumed) + blo(v), bhi(assumed) + bhi(v));
    old = atomicCAS(ap, assumed, nv);
  } while (old != assumed);
}
#endif

#define MFMA16(a, b, c) __builtin_amdgcn_mfma_f32_16x16x32_bf16((a), (b), (c), 0, 0, 0)

// ---------------- prep kernels (memset first, conv last) ----------------

__global__ __launch_bounds__(256) void k_conv_edge(const float* __restrict__ ef,
                                                   u16* __restrict__ ebf) {
  int i = blockIdx.x * 256 + threadIdx.x;  // < 16,000,000
  float4 v = ((const float4*)ef)[i];
  ushort4 o;
  o.x = f2bf(v.x); o.y = f2bf(v.y); o.z = f2bf(v.z); o.w = f2bf(v.w);
  ((ushort4*)ebf)[i] = o;
}

// wt1[n*160+k] = W1[k,n] (k<132 else 0)   [transposed row-major]
// wt2[n*128+k] = g1[k]*W2[k,n]            [transposed row-major]
// wp3[(k>>3)*64 + n][k&7] = g2[k]*W3[k,n] [B-fragment packed]
__global__ __launch_bounds__(256) void k_pack_w(const float* __restrict__ W1,
                                                const float* __restrict__ W2,
                                                const float* __restrict__ W3,
                                                const float* __restrict__ g1,
                                                const float* __restrict__ g2,
                                                u16* __restrict__ wt1,
                                                u16* __restrict__ wt2,
                                                u16* __restrict__ wp3) {
  int i = blockIdx.x * 256 + threadIdx.x;  // < 45056
  if (i < 20480) {
    int n = i / 160, k = i - n * 160;
    wt1[i] = (k < 132) ? f2bf(W1[k * 128 + n]) : (u16)0;
  } else if (i < 36864) {
    int i2 = i - 20480;
    int n = i2 >> 7, k = i2 & 127;
    wt2[i2] = f2bf(g1[k] * W2[k * 128 + n]);
  } else if (i < 45056) {
    int i3 = i - 36864;
    int j = i3 & 7, n = (i3 >> 3) & 63, kb = i3 >> 9;
    int k = kb * 8 + j;
    wp3[i3] = f2bf(g2[k] * W3[k * 64 + n]);
  }
}

__global__ __launch_bounds__(256) void k_pack_vec(
    const float* __restrict__ W2, const float* __restrict__ W3,
    const float* __restrict__ g1, const float* __restrict__ be1, const float* __restrict__ b2,
    const float* __restrict__ g2, const float* __restrict__ be2,
    float* __restrict__ s2, float* __restrict__ c2,
    float* __restrict__ s3, float* __restrict__ t3) {
  int t = threadIdx.x;
  if (t < 128) {
    float a = 0.f, b = 0.f;
    for (int k = 0; k < 128; ++k) {
      float w = W2[k * 128 + t];
      a += g1[k] * w; b += be1[k] * w;
    }
    s2[t] = a; c2[t] = b + b2[t];
  } else if (t < 192) {
    int n = t - 128;
    float a = 0.f, b = 0.f;
    for (int k = 0; k < 128; ++k) {
      float w = W3[k * 64 + n];
      a += g2[k] * w; b += be2[k] * w;
    }
    s3[n] = a; t3[n] = b;
  }
}

// ---------------- main triplet kernel (R13 optimum: (256,5), pk-bf16 atomics) ----------------
// 256 thr = 4 waves (wm:2 hidden-halves x wn:2 trip-halves), 64 triplets/block.
// GEMM1/2 transposed (lane-local LN stats); GEMM1 B-frags gathered from global
// ebf into regs; GEMM3 un-transposed -> coalesced packed-bf16 atomics.
// (256,5): measured no-spill frontier — 6 and 7 blocks/CU both spill (R8/R14).

__global__ __launch_bounds__(256, 5) void k_triplet(
    const u16* __restrict__ ebf, const int* __restrict__ tidx,
    const float* __restrict__ geo,
    const u16* __restrict__ wt1, const u16* __restrict__ wt2, const u16* __restrict__ wp3,
    const float* __restrict__ b1,
    const float* __restrict__ s2v, const float* __restrict__ c2v,
    const float* __restrict__ s3v,
    u16* __restrict__ psum, float* __restrict__ cnt) {
  __shared__ __align__(16) char smem[LDS_TOTAL];
  float* P1S = (float*)(smem + LDS_P1S);
  float* P1Q = (float*)(smem + LDS_P1Q);
  float* P2S = (float*)(smem + LDS_P2S);
  float* P2Q = (float*)(smem + LDS_P2Q);
  int* EIJ = (int*)(smem + LDS_EIJ);

  const int tid = threadIdx.x;
  const int wave = tid >> 6, lane = tid & 63;
  const int wm = wave >> 1, wn = wave & 1;
  const int l15 = lane & 15, lg = lane >> 4;
  const int t0 = blockIdx.x * 64;

  // per-lane trips for the two B-fragment columns (f=0,1)
  const int tA = wn * 32 + l15;
  const int tB = tA + 16;
  int2 pA = ((const int2*)tidx)[t0 + tA];
  int2 pB = ((const int2*)tidx)[t0 + tB];

  // deep-prefetch 8 global B-frag gathers (16B each) for GEMM1 (k<128 part)
  const short8* eb = (const short8*)ebf;
  short8 bxA0 = eb[(size_t)pA.x * 8 + lg];
  short8 bxA1 = eb[(size_t)pA.x * 8 + 4 + lg];
  short8 bxA2 = eb[(size_t)pA.y * 8 + lg];
  short8 bxA3 = eb[(size_t)pA.y * 8 + 4 + lg];
  short8 bxB0 = eb[(size_t)pB.x * 8 + lg];
  short8 bxB1 = eb[(size_t)pB.x * 8 + 4 + lg];
  short8 bxB2 = eb[(size_t)pB.y * 8 + lg];
  short8 bxB3 = eb[(size_t)pB.y * 8 + 4 + lg];

  // stage EIJ + geo tail ([64][64B], swizzle (r&3)<<4)
  if (tid < 64) {
    int2 p = ((const int2*)tidx)[t0 + tid];
    EIJ[tid] = p.x;
    atomicAdd(&cnt[p.x], 1.0f);
    float4 gq = ((const float4*)geo)[t0 + tid];
    uint2 gw; gw.x = pkbf(gq.x, gq.y); gw.y = pkbf(gq.z, gq.w);
    char* tp = smem + LDS_TAIL + tid * 64;
    const int ts = (tid & 3) << 4;
    *(uint2*)(tp + (0 ^ ts)) = gw;
    *(uint2*)(tp + (0 ^ ts) + 8) = (uint2){0, 0};
    *(uint4*)(tp + (16 ^ ts)) = (uint4){0, 0, 0, 0};
    *(uint4*)(tp + (32 ^ ts)) = (uint4){0, 0, 0, 0};
    *(uint4*)(tp + (48 ^ ts)) = (uint4){0, 0, 0, 0};
  }
  __syncthreads();

  short8 btA = *(const short8*)(smem + LDS_TAIL + tA * 64 + ((lg * 16) ^ ((tA & 3) << 4)));
  short8 btB = *(const short8*)(smem + LDS_TAIL + tB * 64 + ((lg * 16) ^ ((tB & 3) << 4)));

  // ---- GEMM1: C1' = W1^T x X^T  (K=160) ----
  f32x4 acc[4][2];
#pragma unroll
  for (int mf = 0; mf < 4; ++mf) { acc[mf][0] = (f32x4)0.f; acc[mf][1] = (f32x4)0.f; }
  const short8* w1p = (const short8*)wt1;
#pragma unroll
  for (int s5 = 0; s5 < 5; ++s5) {
    short8 b0, b1x;
    if (s5 == 0) { b0 = bxA0; b1x = bxB0; }
    else if (s5 == 1) { b0 = bxA1; b1x = bxB1; }
    else if (s5 == 2) { b0 = bxA2; b1x = bxB2; }
    else if (s5 == 3) { b0 = bxA3; b1x = bxB3; }
    else { b0 = btA; b1x = btB; }
#pragma unroll
    for (int mf = 0; mf < 4; ++mf) {
      short8 aw = w1p[(wm * 64 + mf * 16 + l15) * 20 + s5 * 4 + lg];
      acc[mf][0] = MFMA16(aw, b0, acc[mf][0]);
      acc[mf][1] = MFMA16(aw, b1x, acc[mf][1]);
    }
  }

  // epilogue1: bias+silu; lane-local stats; write H^T [trip][n] bf16
  {
    float4 b1f[4];
#pragma unroll
    for (int mf = 0; mf < 4; ++mf)
      b1f[mf] = *(const float4*)(b1 + wm * 64 + mf * 16 + lg * 4);
    float st[2] = {0.f, 0.f}, sq[2] = {0.f, 0.f};
#pragma unroll
    for (int mf = 0; mf < 4; ++mf)
#pragma unroll
      for (int f = 0; f < 2; ++f)
#pragma unroll
        for (int q2 = 0; q2 < 4; ++q2) {
          float v = silu(acc[mf][f][q2] + b1f[mf][q2]);
          acc[mf][f][q2] = v;
          st[f] += v; sq[f] += v * v;
        }
#pragma unroll
    for (int f = 0; f < 2; ++f) {
      st[f] += __shfl_xor(st[f], 16); sq[f] += __shfl_xor(sq[f], 16);
      st[f] += __shfl_xor(st[f], 32); sq[f] += __shfl_xor(sq[f], 32);
    }
    if (lg == 0) {
#pragma unroll
      for (int f = 0; f < 2; ++f) {
        int trip = wn * 32 + f * 16 + l15;
        P1S[trip * 2 + wm] = st[f];
        P1Q[trip * 2 + wm] = sq[f];
      }
    }
#pragma unroll
    for (int mf = 0; mf < 4; ++mf)
#pragma unroll
      for (int f = 0; f < 2; ++f) {
        int trip = wn * 32 + f * 16 + l15;
        uint2 w;
        w.x = pkbf(acc[mf][f][0], acc[mf][f][1]);
        w.y = pkbf(acc[mf][f][2], acc[mf][f][3]);
        *(uint2*)(smem + LDS_HM + trip * 256 +
                  ((wm * 128 + mf * 32 + lg * 8) ^ ((trip & 7) << 4))) = w;
      }
  }
  __syncthreads();

  // ---- GEMM2: C2' = W2'^T x H^T  (K=128) ----
#pragma unroll
  for (int mf = 0; mf < 4; ++mf) { acc[mf][0] = (f32x4)0.f; acc[mf][1] = (f32x4)0.f; }
  const short8* w2p = (const short8*)wt2;
#pragma unroll
  for (int s4 = 0; s4 < 4; ++s4) {
    short8 bx0, bx1;
    {
      int trip = wn * 32 + l15;
      bx0 = *(const short8*)(smem + LDS_HM + trip * 256 +
                             ((s4 * 64 + lg * 16) ^ ((trip & 7) << 4)));
      int trip2 = trip + 16;
      bx1 = *(const short8*)(smem + LDS_HM + trip2 * 256 +
                             ((s4 * 64 + lg * 16) ^ ((trip2 & 7) << 4)));
    }
#pragma unroll
    for (int mf = 0; mf < 4; ++mf) {
      short8 aw = w2p[(wm * 64 + mf * 16 + l15) * 16 + s4 * 4 + lg];
      acc[mf][0] = MFMA16(aw, bx0, acc[mf][0]);
      acc[mf][1] = MFMA16(aw, bx1, acc[mf][1]);
    }
  }

  // epilogue2: folded LN1 + silu; lane-local stats into P2
  {
    float4 s2f[4], c2f[4];
#pragma unroll
    for (int mf = 0; mf < 4; ++mf) {
      s2f[mf] = *(const float4*)(s2v + wm * 64 + mf * 16 + lg * 4);
      c2f[mf] = *(const float4*)(c2v + wm * 64 + mf * 16 + lg * 4);
    }
    float mu[2], inv[2];
#pragma unroll
    for (int f = 0; f < 2; ++f) {
      int trip = wn * 32 + f * 16 + l15;
      float sm = P1S[trip * 2] + P1S[trip * 2 + 1];
      float qq = P1Q[trip * 2] + P1Q[trip * 2 + 1];
      mu[f] = sm * 0.0078125f;
      inv[f] = rsqrtf(fmaxf(qq * 0.0078125f - mu[f] * mu[f], 0.f) + 1e-5f);
    }
    float st[2] = {0.f, 0.f}, sq[2] = {0.f, 0.f};
#pragma unroll
    for (int mf = 0; mf < 4; ++mf)
#pragma unroll
      for (int f = 0; f < 2; ++f)
#pragma unroll
        for (int q2 = 0; q2 < 4; ++q2) {
          float y = inv[f] * (acc[mf][f][q2] - mu[f] * s2f[mf][q2]) + c2f[mf][q2];
          float v = silu(y);
          acc[mf][f][q2] = v;
          st[f] += v; sq[f] += v * v;
        }
#pragma unroll
    for (int f = 0; f < 2; ++f) {
      st[f] += __shfl_xor(st[f], 16); sq[f] += __shfl_xor(sq[f], 16);
      st[f] += __shfl_xor(st[f], 32); sq[f] += __shfl_xor(sq[f], 32);
    }
    if (lg == 0) {
#pragma unroll
      for (int f = 0; f < 2; ++f) {
        int trip = wn * 32 + f * 16 + l15;
        P2S[trip * 2 + wm] = st[f];
        P2Q[trip * 2 + wm] = sq[f];
      }
    }
  }
  __syncthreads();  // all GEMM2 H-reads done; P2 visible

  // write M [trip][n] bf16 into HM region (aliases H)
#pragma unroll
  for (int mf = 0; mf < 4; ++mf)
#pragma unroll
    for (int f = 0; f < 2; ++f) {
      int trip = wn * 32 + f * 16 + l15;
      uint2 w;
      w.x = pkbf(acc[mf][f][0], acc[mf][f][1]);
      w.y = pkbf(acc[mf][f][2], acc[mf][f][3]);
      *(uint2*)(smem + LDS_HM + trip * 256 +
                ((wm * 128 + mf * 32 + lg * 8) ^ ((trip & 7) << 4))) = w;
    }
  __syncthreads();  // M visible

  // ---- GEMM3 (un-transposed): C3 = M x W3'  (K=128, N=64) ----
  f32x4 acc3[4];
#pragma unroll
  for (int nf = 0; nf < 4; ++nf) acc3[nf] = (f32x4)0.f;
  const short8* wb3 = (const short8*)wp3;
#pragma unroll
  for (int s4 = 0; s4 < 4; ++s4) {
    int row = wave * 16 + l15;
    short8 a = *(const short8*)(smem + LDS_HM + row * 256 +
                                ((s4 * 64 + lg * 16) ^ ((row & 7) << 4)));
#pragma unroll
    for (int nf = 0; nf < 4; ++nf) {
      short8 b = wb3[(s4 * 4 + lg) * 64 + nf * 16 + l15];
      acc3[nf] = MFMA16(a, b, acc3[nf]);
    }
  }

  // epilogue3: folded LN2; pair cols across lane-pairs; packed-bf16 atomics.
  {
    float s3c[4];
#pragma unroll
    for (int nf = 0; nf < 4; ++nf) s3c[nf] = s3v[nf * 16 + l15];
    float yv[4][4], yn[4][4];   // [nf][q] — all indices compile-time below
#pragma unroll
    for (int q2 = 0; q2 < 4; ++q2) {
      int row = wave * 16 + lg * 4 + q2;
      float sm = P2S[row * 2] + P2S[row * 2 + 1];
      float qq = P2Q[row * 2] + P2Q[row * 2 + 1];
      float mu = sm * 0.0078125f;
      float inv = rsqrtf(fmaxf(qq * 0.0078125f - mu * mu, 0.f) + 1e-5f);
#pragma unroll
      for (int nf = 0; nf < 4; ++nf)
        yv[nf][q2] = inv * (acc3[nf][q2] - mu * s3c[nf]);
    }
#pragma unroll
    for (int q2 = 0; q2 < 4; ++q2)
#pragma unroll
      for (int nf = 0; nf < 4; ++nf)
        yn[nf][q2] = __shfl_xor(yv[nf][q2], 1);
    const int odd = l15 & 1;
    const int colp = l15 & ~1;   // paired column base within 16
#pragma unroll
    for (int dq = 0; dq < 2; ++dq) {
      int rowE = wave * 16 + lg * 4 + dq;       // even-lane row (q=dq)
      int rowO = rowE + 2;                      // odd-lane row (q=2+dq)
      int row = odd ? rowO : rowE;
      u16* base = psum + (size_t)EIJ[row] * 64 + colp;
#pragma unroll
      for (int nf = 0; nf < 4; ++nf) {
        float lo = odd ? yn[nf][2 + dq] : yv[nf][dq];   // col 2k
        float hi = odd ? yv[nf][2 + dq] : yn[nf][dq];   // col 2k+1
        atomic_pk_add_bf16(base + nf * 16, pkbf(lo, hi));
      }
    }
  }
}

// ---------------- finalize ----------------
// out = LN(bf16(ef) + psum/max(cnt,1) + b3 + (cnt>0 ? t3 : 0), gn, bn)

__global__ __launch_bounds__(256) void k_final(
    const u16* __restrict__ psum, const float* __restrict__ cnt,
    const u16* __restrict__ ebf, const float* __restrict__ b3,
    const float* __restrict__ t3, const float* __restrict__ gn,
    const float* __restrict__ bn, float* __restrict__ out) {
  int g = blockIdx.x * 256 + threadIdx.x;  // 4e6 threads, 4 lanes/edge
  int e = g >> 2, s = g & 3;
  float cv = cnt[e];
  float ic = 1.0f / fmaxf(cv, 1.0f);
  float tw = (cv > 0.f) ? 1.0f : 0.0f;
  float x[16];
  const uint4* ps = (const uint4*)(psum + (size_t)e * 64 + s * 16);
  const uint4* fb = (const uint4*)(ebf + (size_t)e * 64 + s * 16);
  const float4* p3 = (const float4*)(b3 + s * 16);
  const float4* pt = (const float4*)(t3 + s * 16);
  uint4 a0 = ps[0], a1 = ps[1];
  uint4 e0 = fb[0], e1 = fb[1];
  float av[16] = {blo(a0.x), bhi(a0.x), blo(a0.y), bhi(a0.y),
                  blo(a0.z), bhi(a0.z), blo(a0.w), bhi(a0.w),
                  blo(a1.x), bhi(a1.x), blo(a1.y), bhi(a1.y),
                  blo(a1.z), bhi(a1.z), blo(a1.w), bhi(a1.w)};
  float ev[16] = {blo(e0.x), bhi(e0.x), blo(e0.y), bhi(e0.y),
                  blo(e0.z), bhi(e0.z), blo(e0.w), bhi(e0.w),
                  blo(e1.x), bhi(e1.x), blo(e1.y), bhi(e1.y),
                  blo(e1.z), bhi(e1.z), blo(e1.w), bhi(e1.w)};
#pragma unroll
  for (int i = 0; i < 4; ++i) {
    float4 c = p3[i], d = pt[i];
    x[4 * i + 0] = ev[4 * i + 0] + av[4 * i + 0] * ic + c.x + tw * d.x;
    x[4 * i + 1] = ev[4 * i + 1] + av[4 * i + 1] * ic + c.y + tw * d.y;
    x[4 * i + 2] = ev[4 * i + 2] + av[4 * i + 2] * ic + c.z + tw * d.z;
    x[4 * i + 3] = ev[4 * i + 3] + av[4 * i + 3] * ic + c.w + tw * d.w;
  }
  float sum = 0.f, ss = 0.f;
#pragma unroll
  for (int i = 0; i < 16; ++i) { sum += x[i]; ss += x[i] * x[i]; }
  sum += __shfl_xor(sum, 1); ss += __shfl_xor(ss, 1);
  sum += __shfl_xor(sum, 2); ss += __shfl_xor(ss, 2);
  float mu = sum * (1.0f / 64.0f);
  float inv = rsqrtf(ss * (1.0f / 64.0f) - mu * mu + 1e-5f);
  float4* po = (float4*)(out + (size_t)e * 64 + s * 16);
#pragma unroll
  for (int i = 0; i < 4; ++i) {
    float4 gv = ((const float4*)(gn + s * 16))[i];
    float4 bv = ((const float4*)(bn + s * 16))[i];
    float4 o;
    o.x = (x[4 * i + 0] - mu) * inv * gv.x + bv.x;
    o.y = (x[4 * i + 1] - mu) * inv * gv.y + bv.y;
    o.z = (x[4 * i + 2] - mu) * inv * gv.z + bv.z;
    o.w = (x[4 * i + 3] - mu) * inv * gv.w + bv.w;
    po[i] = o;
  }
}

extern "C" void kernel_launch(void* const* d_in, const int* in_sizes, int n_in,
                              void* d_out, int out_size, void* d_ws, size_t ws_size,
                              hipStream_t stream) {
  const float* edge_feat = (const float*)d_in[0];
  const int* tidx = (const int*)d_in[1];
  const float* geo = (const float*)d_in[2];
  const float* W1 = (const float*)d_in[3];
  const float* b1 = (const float*)d_in[4];
  const float* g1 = (const float*)d_in[5];
  const float* be1 = (const float*)d_in[6];
  const float* W2 = (const float*)d_in[7];
  const float* b2 = (const float*)d_in[8];
  const float* g2 = (const float*)d_in[9];
  const float* be2 = (const float*)d_in[10];
  const float* W3 = (const float*)d_in[11];
  const float* b3 = (const float*)d_in[12];
  const float* gn = (const float*)d_in[13];
  const float* bn = (const float*)d_in[14];

  char* ws = (char*)d_ws;
  u16* psum = (u16*)(ws + OFF_PSUM);
  float* cnt = (float*)(ws + OFF_CNT);
  u16* ebf = (u16*)(ws + OFF_EBF);
  u16* wt1 = (u16*)(ws + OFF_WT1);
  u16* wt2 = (u16*)(ws + OFF_WT2);
  u16* wp3 = (u16*)(ws + OFF_WP3);
  float* s2 = (float*)(ws + OFF_S2);
  float* c2 = (float*)(ws + OFF_C2);
  float* s3 = (float*)(ws + OFF_S3);
  float* t3 = (float*)(ws + OFF_T3);
  float* out = (float*)d_out;

  hipMemsetAsync(ws, 0, 132000000ULL, stream);  // psum (bf16) + cnt
  k_conv_edge<<<62500, 256, 0, stream>>>(edge_feat, ebf);
  k_pack_w<<<176, 256, 0, stream>>>(W1, W2, W3, g1, g2, wt1, wt2, wp3);
  k_pack_vec<<<1, 256, 0, stream>>>(W2, W3, g1, be1, b2, g2, be2, s2, c2, s3, t3);

  k_triplet<<<31250, 256, 0, stream>>>(ebf, tidx, geo, wt1, wt2, wp3,
                                       b1, s2, c2, s3, psum, cnt);
  k_final<<<15625, 256, 0, stream>>>(psum, cnt, ebf, b3, t3, gn, bn, out);
}